// Round 4
// baseline (252.275 us; speedup 1.0000x reference)
//
#include <hip/hip_runtime.h>

#define B 64
#define S 512
#define D 768
#define E 32
#define N_ENT (B * E)        // 2048
#define MPE 4
#define M (N_ENT * MPE)      // 8192
#define N_TYPES 6
#define P (B * E * (E - 1))  // 63488

#define D4 (D / 4)                     // 192 float4 slots per row
#define FEAT_SLOTS (P * 3 * D4)        // 36,569,088 float4 slots
#define GRID 2048
#define TYPES_ELEMS (P * N_TYPES)      // 380928
#define TYPES_PER_BLOCK ((TYPES_ELEMS + GRID - 1) / GRID)  // 186

typedef float f32x4 __attribute__((ext_vector_type(4)));

__device__ __forceinline__ float lse4(float a, float b, float c, float d) {
    float mx = fmaxf(fmaxf(a, b), fmaxf(c, d));
    return logf(expf(a - mx) + expf(b - mx) + expf(c - mx) + expf(d - mx)) + mx;
}

// ---------------------------------------------------------------------------
// Single fused kernel.
//  1) Each block first emits its 186-element chunk of pair_types (independent).
//  2) Grid-stride sweep over ALL P*3*D4 output float4 slots, in contiguous
//     order (round-2 lesson: never split this sweep). r==0 copies the cls row;
//     r==1/2 recompute the 4-mention logsumexp inline from hidden — no prep
//     launch, no workspace, no serial dependency. The 4 gathered row segments
//     are L2-resident (the resident block window covers ~1 doc; mention rows
//     per doc = 384 KB) and the exp/log VALU (~12 µs) hides under ~90 µs of
//     write-bound streaming.
// All stores nontemporal; p/r/q are wave-uniform (D4 = 3*64), so index loads
// are broadcast and every read/write is 1 KB-coalesced per wave.
// ---------------------------------------------------------------------------
__global__ __launch_bounds__(256) void fused_kernel(
    const float* __restrict__ hidden,
    const int* __restrict__ mention_entity,
    const int* __restrict__ mention_pos,
    const int* __restrict__ pair_head,
    const int* __restrict__ pair_tail,
    const int* __restrict__ pair_doc,
    const int* __restrict__ ent_type,
    f32x4* __restrict__ out4,
    float* __restrict__ out_types) {
    const unsigned b = blockIdx.x;
    const unsigned t = threadIdx.x;

    // --- pair_types chunk (no dependency on anything below) ---
    {
        const unsigned i = b * TYPES_PER_BLOCK + t;
        if (t < TYPES_PER_BLOCK && i < (unsigned)TYPES_ELEMS) {
            const unsigned p = i / N_TYPES;
            const int ty = (int)(i - p * N_TYPES);
            const int th = ent_type[pair_head[p]];
            const int tt = ent_type[pair_tail[p]];
            out_types[i] = (float)((ty == th) + (ty == tt));
        }
    }

    // --- contiguous feature sweep ---
    const unsigned stride = GRID * 256u;
    for (unsigned idx = b * 256u + t; idx < (unsigned)FEAT_SLOTS; idx += stride) {
        const unsigned p = idx / (3 * D4);          // magic mul
        const unsigned rem = idx - p * (3 * D4);
        const unsigned r = rem / D4;                // 0,1,2 (wave-uniform)
        const unsigned d4 = rem - r * D4;

        f32x4 v;
        if (r == 0) {
            const f32x4* cls4 =
                (const f32x4*)(hidden + (size_t)pair_doc[p] * (S * D));
            v = cls4[d4];
        } else {
            const int q = (r == 1) ? pair_head[p] : pair_tail[p];
            const int mbase = q * MPE;
            const int doc = mention_entity[mbase] / E;   // broadcast load
            const float* rowbase = hidden + (size_t)doc * S * D + (size_t)d4 * 4;
            f32x4 x[MPE];
#pragma unroll
            for (int m = 0; m < MPE; ++m) {
                const int pos = mention_pos[mbase + m] + 1;  // broadcast load
                x[m] = *(const f32x4*)(rowbase + (size_t)pos * D);
            }
            v.x = lse4(x[0].x, x[1].x, x[2].x, x[3].x);
            v.y = lse4(x[0].y, x[1].y, x[2].y, x[3].y);
            v.z = lse4(x[0].z, x[1].z, x[2].z, x[3].z);
            v.w = lse4(x[0].w, x[1].w, x[2].w, x[3].w);
        }
        __builtin_nontemporal_store(v, &out4[idx]);
    }
}

extern "C" void kernel_launch(void* const* d_in, const int* in_sizes, int n_in,
                              void* d_out, int out_size, void* d_ws, size_t ws_size,
                              hipStream_t stream) {
    const float* hidden       = (const float*)d_in[0];
    const int* mention_entity = (const int*)d_in[1];
    const int* mention_pos    = (const int*)d_in[2];
    const int* pair_head      = (const int*)d_in[3];
    const int* pair_tail      = (const int*)d_in[4];
    const int* pair_doc       = (const int*)d_in[5];
    const int* ent_type       = (const int*)d_in[6];

    float* out       = (float*)d_out;
    float* out_types = out + (size_t)P * 3 * D;  // after P*3*D feature floats

    fused_kernel<<<GRID, 256, 0, stream>>>(
        hidden, mention_entity, mention_pos, pair_head, pair_tail, pair_doc,
        ent_type, (f32x4*)out, out_types);
}

// Round 6
// 244.470 us; speedup vs baseline: 1.0319x; 1.0319x over previous
//
#include <hip/hip_runtime.h>

#define B 64
#define S 512
#define D 768
#define E 32
#define N_ENT (B * E)        // 2048
#define MPE 4
#define M (N_ENT * MPE)      // 8192
#define N_TYPES 6
#define P (B * E * (E - 1))  // 63488

#define D4 (D / 4)                  // 192 float4 slots per row
#define FEAT_SLOTS (P * 3 * D4)     // 36,569,088 float4 slots
#define LSE_TASKS (N_ENT * D4)      // 393,216
#define TYPES_ELEMS (P * N_TYPES)   // 380,928
#define GRID 1024                   // <= 4 blocks/CU * 256 CUs -> co-resident
#define NT (GRID * 256)             // 262,144 threads

typedef float f32x4 __attribute__((ext_vector_type(4)));

__device__ __forceinline__ float lse4(float a, float b, float c, float d) {
    float mx = fmaxf(fmaxf(a, b), fmaxf(c, d));
    return logf(expf(a - mx) + expf(b - mx) + expf(c - mx) + expf(d - mx)) + mx;
}

// ---------------------------------------------------------------------------
// Single fused kernel with a MANUAL grid barrier (R4 lesson: cooperative
// launch API rejected the grid; all-zero output = launch never ran).
// Co-residency is guaranteed by construction: __launch_bounds__(256,4)
// forces <=128 VGPR => >=4 blocks/CU => 1024 blocks all resident, so the
// spin barrier cannot deadlock (guide §1 sanctioned pattern).
//  Phase 1: pair_types (independent) + ent[] logsumexp, grid-stride.
//           LSE computed ONCE per entity (R3 lesson: never per pair).
//  Barrier: __syncthreads -> t0 release fence + atomicAdd + acquire spin ->
//           fence -> __syncthreads.  Counter in d_ws, re-zeroed per call.
//  Phase 2: THE contiguous sweep over all P*3*D4 output slots (R2 lesson:
//           never split it). Two iterations paired per loop body for store
//           queue depth at 16 waves/CU. p/r wave-uniform (all strides are
//           multiples of 64): broadcast index loads, 1KB-coalesced reads,
//           streaming nontemporal stores.
// ---------------------------------------------------------------------------
__global__ __launch_bounds__(256, 4) void fused_kernel(
    const float* __restrict__ hidden,
    const int* __restrict__ mention_entity,
    const int* __restrict__ mention_pos,
    const int* __restrict__ pair_head,
    const int* __restrict__ pair_tail,
    const int* __restrict__ pair_doc,
    const int* __restrict__ ent_type,
    float* __restrict__ ent,
    unsigned* __restrict__ barrier_cnt,
    f32x4* __restrict__ out4,
    float* __restrict__ out_types) {
    const unsigned tid = blockIdx.x * 256u + threadIdx.x;

    // --- phase 1a: pair_types (no dependency on ent) ---
    for (unsigned i = tid; i < (unsigned)TYPES_ELEMS; i += (unsigned)NT) {
        const unsigned p = i / N_TYPES;
        const int ty = (int)(i - p * N_TYPES);
        const int th = ent_type[pair_head[p]];
        const int tt = ent_type[pair_tail[p]];
        out_types[i] = (float)((ty == th) + (ty == tt));
    }

    // --- phase 1b: ent logsumexp, one f32x4 per task (1-2 tasks/thread) ---
    for (unsigned i = tid; i < (unsigned)LSE_TASKS; i += (unsigned)NT) {
        const unsigned e = i / D4;                  // wave-uniform
        const unsigned d4 = i - e * D4;
        const int doc = mention_entity[e * MPE] / E;
        const float* rowbase = hidden + (size_t)doc * S * D + (size_t)d4 * 4;

        f32x4 x[MPE];
#pragma unroll
        for (int m = 0; m < MPE; ++m) {
            const int pos = mention_pos[e * MPE + m] + 1;
            x[m] = __builtin_nontemporal_load(
                (const f32x4*)(rowbase + (size_t)pos * D));
        }
        f32x4 o;
        o.x = lse4(x[0].x, x[1].x, x[2].x, x[3].x);
        o.y = lse4(x[0].y, x[1].y, x[2].y, x[3].y);
        o.z = lse4(x[0].z, x[1].z, x[2].z, x[3].z);
        o.w = lse4(x[0].w, x[1].w, x[2].w, x[3].w);
        *(f32x4*)(ent + (size_t)e * D + (size_t)d4 * 4) = o;
    }

    // --- manual grid barrier (all GRID blocks co-resident by construction) ---
    __syncthreads();                     // block's stores drained (vmcnt0 at barrier)
    if (threadIdx.x == 0) {
        __threadfence();                 // device-scope release: L2 writeback
        atomicAdd(barrier_cnt, 1u);
        while (__hip_atomic_load(barrier_cnt, __ATOMIC_ACQUIRE,
                                 __HIP_MEMORY_SCOPE_AGENT) < (unsigned)GRID) {
            __builtin_amdgcn_s_sleep(8);
        }
        __threadfence();                 // acquire side: invalidate stale lines
    }
    __syncthreads();

    // --- phase 2: contiguous feature sweep, 2 slots in flight per thread ---
    for (unsigned idx = tid; idx < (unsigned)FEAT_SLOTS; idx += 2u * NT) {
        const unsigned idx2 = idx + (unsigned)NT;

        const unsigned p1 = idx / (3 * D4);
        const unsigned rem1 = idx - p1 * (3 * D4);
        const unsigned r1 = rem1 / D4;              // wave-uniform
        const unsigned d41 = rem1 - r1 * D4;
        const f32x4* s1;
        if (r1 == 0) {
            s1 = (const f32x4*)(hidden + (size_t)pair_doc[p1] * (S * D));
        } else {
            const int q = (r1 == 1) ? pair_head[p1] : pair_tail[p1];
            s1 = (const f32x4*)(ent + (size_t)q * D);
        }
        const f32x4 v1 = s1[d41];

        if (idx2 < (unsigned)FEAT_SLOTS) {
            const unsigned p2 = idx2 / (3 * D4);
            const unsigned rem2 = idx2 - p2 * (3 * D4);
            const unsigned r2 = rem2 / D4;
            const unsigned d42 = rem2 - r2 * D4;
            const f32x4* s2;
            if (r2 == 0) {
                s2 = (const f32x4*)(hidden + (size_t)pair_doc[p2] * (S * D));
            } else {
                const int q = (r2 == 1) ? pair_head[p2] : pair_tail[p2];
                s2 = (const f32x4*)(ent + (size_t)q * D);
            }
            const f32x4 v2 = s2[d42];
            __builtin_nontemporal_store(v1, &out4[idx]);
            __builtin_nontemporal_store(v2, &out4[idx2]);
        } else {
            __builtin_nontemporal_store(v1, &out4[idx]);
        }
    }
}

extern "C" void kernel_launch(void* const* d_in, const int* in_sizes, int n_in,
                              void* d_out, int out_size, void* d_ws, size_t ws_size,
                              hipStream_t stream) {
    const float* hidden       = (const float*)d_in[0];
    const int* mention_entity = (const int*)d_in[1];
    const int* mention_pos    = (const int*)d_in[2];
    const int* pair_head      = (const int*)d_in[3];
    const int* pair_tail      = (const int*)d_in[4];
    const int* pair_doc       = (const int*)d_in[5];
    const int* ent_type       = (const int*)d_in[6];

    float* out       = (float*)d_out;
    f32x4* out4      = (f32x4*)out;              // P*3*D floats
    float* out_types = out + (size_t)P * 3 * D;  // P*N_TYPES floats

    float* ent            = (float*)d_ws;            // N_ENT*D f32 = 6.29 MB
    unsigned* barrier_cnt = (unsigned*)(ent + (size_t)N_ENT * D);

    // Re-zero the barrier counter every call (graph replays included).
    hipMemsetAsync(barrier_cnt, 0, sizeof(unsigned), stream);

    fused_kernel<<<GRID, 256, 0, stream>>>(
        hidden, mention_entity, mention_pos, pair_head, pair_tail, pair_doc,
        ent_type, ent, barrier_cnt, out4, out_types);
}

// Round 7
// 103.978 us; speedup vs baseline: 2.4262x; 2.3512x over previous
//
#include <hip/hip_runtime.h>

#define B 64
#define S 512
#define D 768
#define E 32
#define N_ENT (B * E)        // 2048
#define MPE 4
#define M (N_ENT * MPE)      // 8192
#define N_TYPES 6
#define P (B * E * (E - 1))  // 63488

#define D4 (D / 4)                     // 192 float4 slots per row
#define LSE_BLOCKS (N_ENT * D4 / 256)  // 1536 (exactly one f32x4/thread)
#define FEAT_SLOTS (P * 3 * D4)        // 36,569,088 float4 slots
#define TYPES_ELEMS (P * N_TYPES)      // 380,928
#define SWEEP_GRID 2048
#define SWEEP_NT (SWEEP_GRID * 256)    // 524,288 threads

typedef float f32x4 __attribute__((ext_vector_type(4)));

__device__ __forceinline__ float lse4(float a, float b, float c, float d) {
    float mx = fmaxf(fmaxf(a, b), fmaxf(c, d));
    return logf(expf(a - mx) + expf(b - mx) + expf(c - mx) + expf(d - mx)) + mx;
}

// ---------------------------------------------------------------------------
// Kernel A — LSE only (serial prefix minimized: types moved out).
// Exactly one f32x4 per thread; e is wave-uniform (192 = 3*64) so index
// loads scalarize; 4 independent gathers issue in parallel.
// R3 lesson: LSE once per entity, never per pair. R5 lesson: no grid-wide
// barrier/fusion — device-scope spin storms L2 invalidates.
// ---------------------------------------------------------------------------
__global__ __launch_bounds__(256) void lse_kernel(
    const float* __restrict__ hidden,
    const int* __restrict__ mention_entity,
    const int* __restrict__ mention_pos,
    float* __restrict__ ent) {
    const unsigned idx = blockIdx.x * 256u + threadIdx.x;  // over N_ENT*D4
    const unsigned e = idx / D4;
    const unsigned d4 = idx - e * D4;
    const int doc = mention_entity[e * MPE] / E;
    const float* rowbase = hidden + (size_t)doc * S * D + (size_t)d4 * 4;

    f32x4 x[MPE];
#pragma unroll
    for (int m = 0; m < MPE; ++m) {
        const int pos = mention_pos[e * MPE + m] + 1;
        x[m] = *(const f32x4*)(rowbase + (size_t)pos * D);
    }
    f32x4 o;
    o.x = lse4(x[0].x, x[1].x, x[2].x, x[3].x);
    o.y = lse4(x[0].y, x[1].y, x[2].y, x[3].y);
    o.z = lse4(x[0].z, x[1].z, x[2].z, x[3].z);
    o.w = lse4(x[0].w, x[1].w, x[2].w, x[3].w);
    *(f32x4*)(ent + (size_t)e * D + (size_t)d4 * 4) = o;
}

// ---------------------------------------------------------------------------
// Kernel B — tiny types prologue (independent of ent) + THE contiguous
// sweep, byte-for-byte R1's loop (single slot per iteration so the compiler
// keeps its load->NT-store pipeline; R5 lesson: paired stores defeat it
// because loads and stores share the vmcnt FIFO). R2 lesson: never split
// the sweep. p/r wave-uniform; broadcast index loads; 1KB-coalesced reads;
// streaming nontemporal stores.
// ---------------------------------------------------------------------------
__global__ __launch_bounds__(256) void sweep_kernel(
    const float* __restrict__ hidden,
    const int* __restrict__ pair_head,
    const int* __restrict__ pair_tail,
    const int* __restrict__ pair_doc,
    const int* __restrict__ ent_type,
    const float* __restrict__ ent,
    f32x4* __restrict__ out4,
    float* __restrict__ out_types) {
    const unsigned tid = blockIdx.x * 256u + threadIdx.x;

    // --- types prologue: <=1 element per thread (380,928 < 524,288) ---
    if (tid < (unsigned)TYPES_ELEMS) {
        const unsigned p = tid / N_TYPES;
        const int ty = (int)(tid - p * N_TYPES);
        const int th = ent_type[pair_head[p]];
        const int tt = ent_type[pair_tail[p]];
        out_types[tid] = (float)((ty == th) + (ty == tt));
    }

    // --- the contiguous feature sweep (R1's exact loop) ---
    for (unsigned idx = tid; idx < (unsigned)FEAT_SLOTS; idx += (unsigned)SWEEP_NT) {
        const unsigned p = idx / (3 * D4);          // magic mul
        const unsigned rem = idx - p * (3 * D4);
        const unsigned r = rem / D4;                // 0,1,2 (wave-uniform)
        const unsigned d4 = rem - r * D4;

        const f32x4* src;
        if (r == 0) {
            src = (const f32x4*)(hidden + (size_t)pair_doc[p] * (S * D));
        } else {
            const int q = (r == 1) ? pair_head[p] : pair_tail[p];
            src = (const f32x4*)(ent + (size_t)q * D);
        }
        __builtin_nontemporal_store(src[d4], &out4[idx]);
    }
}

extern "C" void kernel_launch(void* const* d_in, const int* in_sizes, int n_in,
                              void* d_out, int out_size, void* d_ws, size_t ws_size,
                              hipStream_t stream) {
    const float* hidden       = (const float*)d_in[0];
    const int* mention_entity = (const int*)d_in[1];
    const int* mention_pos    = (const int*)d_in[2];
    const int* pair_head      = (const int*)d_in[3];
    const int* pair_tail      = (const int*)d_in[4];
    const int* pair_doc       = (const int*)d_in[5];
    const int* ent_type       = (const int*)d_in[6];

    float* out       = (float*)d_out;
    f32x4* out4      = (f32x4*)out;              // P*3*D floats
    float* out_types = out + (size_t)P * 3 * D;  // P*N_TYPES floats
    float* ent       = (float*)d_ws;             // N_ENT*D floats = 6.3 MB

    lse_kernel<<<LSE_BLOCKS, 256, 0, stream>>>(
        hidden, mention_entity, mention_pos, ent);

    sweep_kernel<<<SWEEP_GRID, 256, 0, stream>>>(
        hidden, pair_head, pair_tail, pair_doc, ent_type, ent,
        out4, out_types);
}